// Round 18
// baseline (338.111 us; speedup 1.0000x reference)
//
#include <hip/hip_runtime.h>
#include <hip/hip_bf16.h>

typedef _Float16 f16x8 __attribute__((ext_vector_type(8)));
typedef float f32x4 __attribute__((ext_vector_type(4)));
typedef unsigned long long ull;

#define UNITS   2048
#define NC      6144
#define TSTEPS  32
#define HSTRIDE 131072   // one h buffer: 64 seqs x 2048 units fp16 (blocked layout)

__device__ __forceinline__ float sigmoid_f(float v){ return 1.0f/(1.0f+__expf(-v)); }
__device__ __forceinline__ float tanh_f(float v){ return 2.0f/(1.0f+__expf(-2.0f*v)) - 1.0f; }

// ---- prep: cast x to fp16; init ring[0] (blocked [u>>3][s][u&7]); zero flags ----
__global__ __launch_bounds__(256) void prep_misc(
    const float* __restrict__ x, const float* __restrict__ h0,
    _Float16* __restrict__ xh, _Float16* __restrict__ hRing,
    unsigned* __restrict__ bar)
{
  int i = blockIdx.x*256 + threadIdx.x;
  if (i < 640) bar[i] = 0;
  if (i < 524288) xh[i] = (_Float16)x[i];
  if (i < 131072) {
    int s = i >> 11, u = i & 2047;
    float v = h0[((s & 7) << 11) + u];
    hRing[(((u >> 3) << 6) + s)*8 + (u & 7)] = (_Float16)v;
  }
}

// ---- two-round phase boundary: wbl2-release, arrive, inv-acquire, arrive ----
// Round 2 guarantees no block writes while another still invalidates.
__device__ __forceinline__ void phase_boundary(unsigned* ctr, unsigned nb)
{
  asm volatile("s_waitcnt vmcnt(0)" ::: "memory");   // per-wave: stores are in L2
  __syncthreads();
  if (threadIdx.x == 0) {
    __builtin_amdgcn_fence(__ATOMIC_RELEASE, "agent");  // buffer_wbl2: L2 -> MALL
    __hip_atomic_fetch_add(ctr, 1u, __ATOMIC_RELAXED, __HIP_MEMORY_SCOPE_AGENT);
    while (__hip_atomic_load(ctr, __ATOMIC_RELAXED, __HIP_MEMORY_SCOPE_AGENT) < nb)
      __builtin_amdgcn_s_sleep(1);
    __builtin_amdgcn_fence(__ATOMIC_ACQUIRE, "agent");  // buffer_inv
    __hip_atomic_fetch_add(ctr, 1u, __ATOMIC_RELAXED, __HIP_MEMORY_SCOPE_AGENT);
    while (__hip_atomic_load(ctr, __ATOMIC_RELAXED, __HIP_MEMORY_SCOPE_AGENT) < 2u*nb)
      __builtin_amdgcn_s_sleep(1);
  }
  __syncthreads();
}

// ---- tree barrier, merged root/publication (champion, unchanged) ----
__device__ __forceinline__ void half_barrier(unsigned* bar, int half, int idxInHalf, int t)
{
  __syncthreads();   // compiler emits s_waitcnt vmcnt(0) here: h stores at MALL
  if (threadIdx.x == 0) {
    unsigned* grp  = bar + (half*8 + (idxInHalf & 7))*32;
    unsigned* root = bar + (16 + half)*32;
    unsigned tgt = (unsigned)(t + 1);
    unsigned a = __hip_atomic_fetch_add(grp, 1u, __ATOMIC_RELAXED, __HIP_MEMORY_SCOPE_AGENT) + 1u;
    if (a == tgt*16u)
      __hip_atomic_fetch_add(root, 1u, __ATOMIC_RELAXED, __HIP_MEMORY_SCOPE_AGENT);
    while (__hip_atomic_load(root, __ATOMIC_RELAXED, __HIP_MEMORY_SCOPE_AGENT) < tgt*8u)
      __builtin_amdgcn_s_sleep(1);
  }
  __syncthreads();
  __builtin_amdgcn_fence(__ATOMIC_ACQUIRE, "workgroup");
}

// ---- all-in-one cooperative kernel: transpose -> xp GEMM -> recurrence ----
__global__ __launch_bounds__(512, 2) void gru_all(
    const float* __restrict__ W, const float* __restrict__ U,
    const float* __restrict__ b, const float* __restrict__ h0,
    const _Float16* __restrict__ xh,
    _Float16* __restrict__ Wt, _Float16* __restrict__ Ut, _Float16* __restrict__ xpf,
    _Float16* __restrict__ hRing,
    float* __restrict__ ret, float* __restrict__ st, unsigned* __restrict__ bar)
{
  __shared__ __align__(16) float sRed[48*288];   // 55.3 KB, aliased per phase
  int tid = threadIdx.x;
  int bid = blockIdx.x;
  unsigned nb = gridDim.x;

  // ======== Phase T: transpose+cast, 24 tiles of 64x64 per block ========
  {
    float (*tile)[65] = (float(*)[65])sRed;      // 16.6 KB
    for (int i = 0; i < 24; ++i) {
      int lin = bid*24 + i;
      int z = lin / 3072, rem = lin - z*3072;
      int n0 = (rem % 96)*64, k0 = (rem / 96)*64;
      const float* src = z ? U : W;
      _Float16* dst = z ? Ut : Wt;
      __syncthreads();
      #pragma unroll
      for (int p = 0; p < 2; ++p) {
        int r = p*32 + (tid >> 4);
        int nq = tid & 15;
        f32x4 v = *(const f32x4*)(src + (size_t)(k0+r)*NC + n0 + nq*4);
        tile[r][nq*4+0] = v[0];
        tile[r][nq*4+1] = v[1];
        tile[r][nq*4+2] = v[2];
        tile[r][nq*4+3] = v[3];
      }
      __syncthreads();
      {
        int row = tid >> 3, k8 = (tid & 7)*8;
        f16x8 o;
        #pragma unroll
        for (int j = 0; j < 8; ++j) o[j] = (_Float16)tile[k8+j][row];
        *(f16x8*)(dst + (size_t)(n0+row)*UNITS + k0 + k8) = o;
      }
    }
  }
  phase_boundary(bar + 576, nb);

  // ======== Phase A: xp GEMM (R16 xp_gemm body, blocks 0..191) ========
  if (bid < 192) {
    short* sB = (short*)sRed;                    // 32 KB
    int n0 = (bid % 96)*64, bt0 = (bid / 96)*128;
    int lane = tid & 63, w = tid >> 6;
    int wm = w & 3, wn = w >> 2;
    int nl = lane & 15, kg = lane >> 4;
    f32x4 acc[2][2] = {{{0,0,0,0},{0,0,0,0}},{{0,0,0,0},{0,0,0,0}}};
    for (int l = 0; l < 8; ++l) {
      __syncthreads();
      #pragma unroll
      for (int i = 0; i < 4; ++i) {
        int e = tid + i*512;
        int col = e >> 5, ch = e & 31;
        f16x8 v = *(const f16x8*)(Wt + (size_t)(n0+col)*UNITS + l*256 + ch*8);
        int off = ((col<<9) | (ch<<4)) ^ ((col&7)<<4);
        *(f16x8*)((char*)sB + off) = v;
      }
      __syncthreads();
      #pragma unroll
      for (int kk = 0; kk < 256; kk += 32) {
        f16x8 a[2];
        #pragma unroll
        for (int sub = 0; sub < 2; ++sub) {
          int row = bt0 + wm*32 + sub*16 + nl;
          a[sub] = *(const f16x8*)(xh + ((size_t)row*8 + l)*256 + kg*8 + kk);
        }
        #pragma unroll
        for (int nt = 0; nt < 2; ++nt) {
          int col = wn*32 + nt*16 + nl;
          int off = ((col<<9) | ((kk + kg*8)<<1)) ^ ((col&7)<<4);
          f16x8 bfr = *(const f16x8*)((const char*)sB + off);
          #pragma unroll
          for (int sub = 0; sub < 2; ++sub)
            acc[sub][nt] = __builtin_amdgcn_mfma_f32_16x16x32_f16(a[sub], bfr, acc[sub][nt], 0,0,0);
        }
      }
      #pragma unroll
      for (int sub = 0; sub < 2; ++sub) {
        int orow = bt0 + wm*32 + sub*16 + kg*4;
        #pragma unroll
        for (int nt = 0; nt < 2; ++nt) {
          int col = n0 + wn*32 + nt*16 + nl;
          float bv = b[col];
          #pragma unroll
          for (int r = 0; r < 4; ++r) {
            int rr = orow + r;
            int b_ = rr >> 5, t_ = rr & 31;
            xpf[(size_t)((l*8 + b_)*32 + t_)*NC + col] = (_Float16)(acc[sub][nt][r] + bv);
          }
        }
      }
    }
  }
  phase_boundary(bar + 608, nb);

  // ======== Phase R: recurrence (champion, byte-identical) ========
  int lane = tid & 63, kq = tid >> 6;
  int half = bid & 1;
  int idxInHalf = bid >> 1;
  int u0 = idxInHalf * 16;
  int s0 = half * 32;
  int nl = lane & 15, kg = lane >> 4;
  int redidx = lane*4 + (lane>>3)*4;

  f16x8 uw[3][8];
  #pragma unroll
  for (int g = 0; g < 3; ++g)
    #pragma unroll
    for (int kk = 0; kk < 8; ++kk) {
      uw[g][kk] = *(const f16x8*)(Ut + (size_t)(g*UNITS + u0 + nl)*UNITS + kq*256 + kk*32 + kg*8);
      asm volatile("" : "+v"(uw[g][kk]));
    }

  int s_local = tid >> 4, u_local = tid & 15;
  int sg = s0 + s_local;
  int u  = u0 + u_local;
  int mE = s_local >> 4, kgE = (s_local >> 2) & 3, rE = s_local & 3;
  int laneE = kgE*16 + u_local;
  int ridxE = laneE*4 + (laneE>>3)*4 + rE;
  int mm = u0 >> 8;

  const float* brec = b + NC;
  float bz = brec[u], br = brec[2048+u], bh = brec[4096+u];
  float hprev = h0[((sg & 7) << 11) + u];

  for (int t = 0; t < TSTEPS; ++t) {
    const _Float16* hc = hRing + (size_t)t*HSTRIDE;
    _Float16*       hn = hRing + (size_t)(t+1)*HSTRIDE;

    const _Float16* xrow = xpf + ((size_t)sg*32 + t)*NC;
    float xz  = (float)xrow[u];
    float xr  = (float)xrow[2048+u];
    float xhv = (float)xrow[4096+u];

    f32x4 a0z={0,0,0,0}, a0r={0,0,0,0}, a0h={0,0,0,0};
    f32x4 a1z={0,0,0,0}, a1r={0,0,0,0}, a1h={0,0,0,0};
    const _Float16* Ab = hc + (size_t)(((kq*32 + kg)*64) + s0 + nl)*8;
    #pragma unroll
    for (int kk = 0; kk < 8; ++kk) {
      f16x8 av0 = *(const f16x8*)(Ab + kk*2048);
      f16x8 av1 = *(const f16x8*)(Ab + kk*2048 + 128);
      a0z = __builtin_amdgcn_mfma_f32_16x16x32_f16(av0, uw[0][kk], a0z, 0,0,0);
      a1z = __builtin_amdgcn_mfma_f32_16x16x32_f16(av1, uw[0][kk], a1z, 0,0,0);
      a0r = __builtin_amdgcn_mfma_f32_16x16x32_f16(av0, uw[1][kk], a0r, 0,0,0);
      a1r = __builtin_amdgcn_mfma_f32_16x16x32_f16(av1, uw[1][kk], a1r, 0,0,0);
      a0h = __builtin_amdgcn_mfma_f32_16x16x32_f16(av0, uw[2][kk], a0h, 0,0,0);
      a1h = __builtin_amdgcn_mfma_f32_16x16x32_f16(av1, uw[2][kk], a1h, 0,0,0);
    }

    {
      float* rp0 = &sRed[((kq*2 + 0)*3)*288 + redidx];
      *(f32x4*)(rp0)        = a0z;
      *(f32x4*)(rp0 + 288)  = a0r;
      *(f32x4*)(rp0 + 576)  = a0h;
      float* rp1 = &sRed[((kq*2 + 1)*3)*288 + redidx];
      *(f32x4*)(rp1)        = a1z;
      *(f32x4*)(rp1 + 288)  = a1r;
      *(f32x4*)(rp1 + 576)  = a1h;
    }
    __syncthreads();

    {
      float vz = 0.f, vr = 0.f, vh = 0.f;
      #pragma unroll
      for (int q = 0; q < 8; ++q) {
        const float* base = &sRed[((q*2 + mE)*3)*288 + ridxE];
        vz += base[0];
        vr += base[288];
        vh += base[576];
      }
      float z   = sigmoid_f(xz  + vz + bz);
      float rg  = sigmoid_f(xr  + vr + br);
      float hh  = tanh_f(xhv + rg*(vh + bh));
      float hnv = z*hprev + (1.0f - z)*hh;
      hprev = hnv;
      _Float16 hb = (_Float16)hnv;
      __hip_atomic_store((unsigned short*)hn + (size_t)(((u >> 3) << 6) + sg)*8 + (u & 7),
                         __builtin_bit_cast(unsigned short, hb),
                         __ATOMIC_RELAXED, __HIP_MEMORY_SCOPE_AGENT);
      if ((sg >> 3) == mm)
        ret[(size_t)((((sg & 7)*32 + t) << 3) + mm)*256 + (u & 255)] = hnv;
      if (t == 31 && sg >= 56)
        st[(size_t)(sg - 56)*UNITS + u] = hnv;
    }
    if (t < TSTEPS - 1)
      half_barrier(bar, half, idxInHalf, t);
  }
}

extern "C" void kernel_launch(void* const* d_in, const int* in_sizes, int n_in,
                              void* d_out, int out_size, void* d_ws, size_t ws_size,
                              hipStream_t stream) {
  const float* x  = (const float*)d_in[0];
  const float* h0 = (const float*)d_in[1];
  const float* W  = (const float*)d_in[2];
  const float* U  = (const float*)d_in[3];
  const float* b  = (const float*)d_in[4];
  float* ret = (float*)d_out;
  float* st  = ret + 524288;

  char* p = (char*)d_ws;
  _Float16* Ut = (_Float16*)p; p += 25165824;
  _Float16* Wt = (_Float16*)p; p += 25165824;
  _Float16* xh = (_Float16*)p; p += 1048576;
  _Float16* xpf = (_Float16*)p; p += 25165824;              // 64x32x6144 f16
  _Float16* hRing = (_Float16*)p; p += 33ull * HSTRIDE * 2; // 8.25 MB
  unsigned* bar = (unsigned*)p; p += 2560;

  prep_misc<<<2048, 256, 0, stream>>>(x, h0, xh, hRing, bar);

  void* args[] = { (void*)&W, (void*)&U, (void*)&b, (void*)&h0, (void*)&xh,
                   (void*)&Wt, (void*)&Ut, (void*)&xpf,
                   (void*)&hRing, (void*)&ret, (void*)&st, (void*)&bar };
  hipLaunchCooperativeKernel((const void*)gru_all, dim3(256), dim3(512),
                             args, 0, stream);
}

// Round 19
// 272.190 us; speedup vs baseline: 1.2422x; 1.2422x over previous
//
#include <hip/hip_runtime.h>
#include <hip/hip_bf16.h>

typedef _Float16 f16x8 __attribute__((ext_vector_type(8)));
typedef float f32x4 __attribute__((ext_vector_type(4)));
typedef unsigned long long ull;

#define UNITS   2048
#define NC      6144
#define TSTEPS  32
#define HSTRIDE 131072   // one h buffer: 64 seqs x 2048 units fp16 (blocked layout)

__device__ __forceinline__ float sigmoid_f(float v){ return 1.0f/(1.0f+__expf(-v)); }
__device__ __forceinline__ float tanh_f(float v){ return 2.0f/(1.0f+__expf(-2.0f*v)) - 1.0f; }

// ---- fused transpose+prep: W,U (2048x6144 f32) -> Wt,Ut (6144x2048 f16);
//      side-band: x cast, hRing[0] init, barrier zero (R16, unchanged) ----
__global__ __launch_bounds__(256) void transpose_prep(
    const float* __restrict__ W, const float* __restrict__ U,
    _Float16* __restrict__ Wt, _Float16* __restrict__ Ut,
    const float* __restrict__ x, const float* __restrict__ h0,
    _Float16* __restrict__ xh, _Float16* __restrict__ hRing,
    unsigned* __restrict__ bar)
{
  __shared__ float tile[64][65];
  int tid = threadIdx.x;
  int lin = blockIdx.x + 96*(blockIdx.y + 32*blockIdx.z);

  if (lin < 2048) {
    int i = lin*256 + tid;
    xh[i] = (_Float16)x[i];
  } else if (lin < 2560) {
    int i = (lin - 2048)*256 + tid;
    int s = i >> 11, u = i & 2047;
    float v = h0[((s & 7) << 11) + u];
    hRing[(((u >> 3) << 6) + s)*8 + (u & 7)] = (_Float16)v;
  } else if (lin == 2560) {
    for (int i = tid; i < 640; i += 256) bar[i] = 0;
  }

  const float* src = blockIdx.z ? U : W;
  _Float16* dst = blockIdx.z ? Ut : Wt;
  int n0 = blockIdx.x*64, k0 = blockIdx.y*64;

  #pragma unroll
  for (int p = 0; p < 4; ++p) {
    int r = p*16 + (tid >> 4);
    int nq = tid & 15;
    f32x4 v = *(const f32x4*)(src + (size_t)(k0+r)*NC + n0 + nq*4);
    tile[r][nq*4+0] = v[0];
    tile[r][nq*4+1] = v[1];
    tile[r][nq*4+2] = v[2];
    tile[r][nq*4+3] = v[3];
  }
  __syncthreads();
  #pragma unroll
  for (int p = 0; p < 2; ++p) {
    int row = p*32 + (tid >> 3);
    int k8 = (tid & 7)*8;
    f16x8 o;
    #pragma unroll
    for (int j = 0; j < 8; ++j) o[j] = (_Float16)tile[k8+j][row];
    *(f16x8*)(dst + (size_t)(n0+row)*UNITS + k0 + k8) = o;
  }
}

// ---- xp GEMM: grid (192 n-tiles of 32, 2 bt-halves of 128 rows), 512 threads ----
// 384 blocks (1.5/CU), 16 KB LDS B-tile; same traffic totals as 64-wide tiles.
__global__ __launch_bounds__(512) void xp_gemm(
    const _Float16* __restrict__ xh, const _Float16* __restrict__ Wt,
    const float* __restrict__ bin, _Float16* __restrict__ xpf)
{
  __shared__ __align__(16) short sB[32*256];   // 16 KB, [col][k256] swizzled
  int n0 = blockIdx.x*32, bt0 = blockIdx.y*128;
  int tid = threadIdx.x;
  int lane = tid & 63, w = tid >> 6;
  int wm = w & 3, wn = w >> 2;                 // 4 row-groups x 2 col-groups
  int nl = lane & 15, kg = lane >> 4;
  f32x4 acc[2] = {{0,0,0,0},{0,0,0,0}};
  for (int l = 0; l < 8; ++l) {
    __syncthreads();
    #pragma unroll
    for (int i = 0; i < 2; ++i) {
      int e = tid + i*512;                     // 1024 chunks: col=e>>5, ch=e&31
      int col = e >> 5, ch = e & 31;
      f16x8 v = *(const f16x8*)(Wt + (size_t)(n0+col)*UNITS + l*256 + ch*8);
      int off = ((col<<9) | (ch<<4)) ^ ((col&7)<<4);
      *(f16x8*)((char*)sB + off) = v;
    }
    __syncthreads();
    #pragma unroll
    for (int kk = 0; kk < 256; kk += 32) {
      f16x8 a[2];
      #pragma unroll
      for (int sub = 0; sub < 2; ++sub) {
        int row = bt0 + wm*32 + sub*16 + nl;
        a[sub] = *(const f16x8*)(xh + ((size_t)row*8 + l)*256 + kg*8 + kk);
      }
      int col = wn*16 + nl;
      int off = ((col<<9) | ((kk + kg*8)<<1)) ^ ((col&7)<<4);
      f16x8 bfr = *(const f16x8*)((const char*)sB + off);
      #pragma unroll
      for (int sub = 0; sub < 2; ++sub)
        acc[sub] = __builtin_amdgcn_mfma_f32_16x16x32_f16(a[sub], bfr, acc[sub], 0,0,0);
    }
    #pragma unroll
    for (int sub = 0; sub < 2; ++sub) {
      int orow = bt0 + wm*32 + sub*16 + kg*4;
      int col = n0 + wn*16 + nl;
      float bv = bin[col];
      #pragma unroll
      for (int r = 0; r < 4; ++r) {
        int rr = orow + r;
        int b_ = rr >> 5, t_ = rr & 31;
        xpf[(size_t)((l*8 + b_)*32 + t_)*NC + col] = (_Float16)(acc[sub][r] + bv);
      }
    }
  }
}

// ---- tree barrier, merged root/publication (champion, unchanged) ----
__device__ __forceinline__ void half_barrier(unsigned* bar, int half, int idxInHalf, int t)
{
  __syncthreads();   // compiler emits s_waitcnt vmcnt(0) here: h stores at MALL
  if (threadIdx.x == 0) {
    unsigned* grp  = bar + (half*8 + (idxInHalf & 7))*32;
    unsigned* root = bar + (16 + half)*32;
    unsigned tgt = (unsigned)(t + 1);
    unsigned a = __hip_atomic_fetch_add(grp, 1u, __ATOMIC_RELAXED, __HIP_MEMORY_SCOPE_AGENT) + 1u;
    if (a == tgt*16u)
      __hip_atomic_fetch_add(root, 1u, __ATOMIC_RELAXED, __HIP_MEMORY_SCOPE_AGENT);
    while (__hip_atomic_load(root, __ATOMIC_RELAXED, __HIP_MEMORY_SCOPE_AGENT) < tgt*8u)
      __builtin_amdgcn_s_sleep(1);
  }
  __syncthreads();
  __builtin_amdgcn_fence(__ATOMIC_ACQUIRE, "workgroup");
}

// ---- persistent GRU (champion, byte-identical to R14/R16) ----
__global__ __launch_bounds__(512, 2) void gru_persist(
    const _Float16* __restrict__ Ut, const _Float16* __restrict__ xpf,
    const float* __restrict__ brec, const float* __restrict__ h0,
    _Float16* __restrict__ hRing,
    float* __restrict__ ret, float* __restrict__ st, unsigned* __restrict__ bar)
{
  __shared__ __align__(16) float sRed[48*288];   // 55.3 KB padded partials

  int tid = threadIdx.x;
  int lane = tid & 63, kq = tid >> 6;       // 8 waves = 8 k-slices of 256
  int half = blockIdx.x & 1;
  int idxInHalf = blockIdx.x >> 1;
  int u0 = idxInHalf * 16;
  int s0 = half * 32;
  int nl = lane & 15, kg = lane >> 4;
  int redidx = lane*4 + (lane>>3)*4;

  // U fragments resident: 24 x f16x8 = 96 regs, pinned against remat
  f16x8 uw[3][8];
  #pragma unroll
  for (int g = 0; g < 3; ++g)
    #pragma unroll
    for (int kk = 0; kk < 8; ++kk) {
      uw[g][kk] = *(const f16x8*)(Ut + (size_t)(g*UNITS + u0 + nl)*UNITS + kq*256 + kk*32 + kg*8);
      asm volatile("" : "+v"(uw[g][kk]));
    }

  // flat epilogue ownership: thread -> (s_local = tid>>4, u_local = tid&15)
  int s_local = tid >> 4, u_local = tid & 15;
  int sg = s0 + s_local;
  int u  = u0 + u_local;
  int mE = s_local >> 4, kgE = (s_local >> 2) & 3, rE = s_local & 3;
  int laneE = kgE*16 + u_local;
  int ridxE = laneE*4 + (laneE>>3)*4 + rE;
  int mm = u0 >> 8;

  float bz = brec[u], br = brec[2048+u], bh = brec[4096+u];
  float hprev = h0[((sg & 7) << 11) + u];

  for (int t = 0; t < TSTEPS; ++t) {
    const _Float16* hc = hRing + (size_t)t*HSTRIDE;
    _Float16*       hn = hRing + (size_t)(t+1)*HSTRIDE;

    // xp(t) loads issue before the MFMA chain; latency hides under it
    const _Float16* xrow = xpf + ((size_t)sg*32 + t)*NC;
    float xz  = (float)xrow[u];
    float xr  = (float)xrow[2048+u];
    float xhv = (float)xrow[4096+u];

    f32x4 a0z={0,0,0,0}, a0r={0,0,0,0}, a0h={0,0,0,0};
    f32x4 a1z={0,0,0,0}, a1r={0,0,0,0}, a1h={0,0,0,0};
    // blocked layout: elem (s,k) at ((k>>3)*64 + s)*8 + (k&7); coalesced b128
    const _Float16* Ab = hc + (size_t)(((kq*32 + kg)*64) + s0 + nl)*8;
    #pragma unroll
    for (int kk = 0; kk < 8; ++kk) {
      f16x8 av0 = *(const f16x8*)(Ab + kk*2048);
      f16x8 av1 = *(const f16x8*)(Ab + kk*2048 + 128);
      a0z = __builtin_amdgcn_mfma_f32_16x16x32_f16(av0, uw[0][kk], a0z, 0,0,0);
      a1z = __builtin_amdgcn_mfma_f32_16x16x32_f16(av1, uw[0][kk], a1z, 0,0,0);
      a0r = __builtin_amdgcn_mfma_f32_16x16x32_f16(av0, uw[1][kk], a0r, 0,0,0);
      a1r = __builtin_amdgcn_mfma_f32_16x16x32_f16(av1, uw[1][kk], a1r, 0,0,0);
      a0h = __builtin_amdgcn_mfma_f32_16x16x32_f16(av0, uw[2][kk], a0h, 0,0,0);
      a1h = __builtin_amdgcn_mfma_f32_16x16x32_f16(av1, uw[2][kk], a1h, 0,0,0);
    }

    // publish partials (16 slots: kq*2 + seq-half-of-32)
    {
      float* rp0 = &sRed[((kq*2 + 0)*3)*288 + redidx];
      *(f32x4*)(rp0)        = a0z;
      *(f32x4*)(rp0 + 288)  = a0r;
      *(f32x4*)(rp0 + 576)  = a0h;
      float* rp1 = &sRed[((kq*2 + 1)*3)*288 + redidx];
      *(f32x4*)(rp1)        = a1z;
      *(f32x4*)(rp1 + 288)  = a1r;
      *(f32x4*)(rp1 + 576)  = a1h;
    }
    __syncthreads();

    // flat epilogue: 512 threads, each reduces 8 partials for its (s,u)
    {
      float vz = 0.f, vr = 0.f, vh = 0.f;
      #pragma unroll
      for (int q = 0; q < 8; ++q) {
        const float* base = &sRed[((q*2 + mE)*3)*288 + ridxE];
        vz += base[0];
        vr += base[288];
        vh += base[576];
      }
      float z   = sigmoid_f(xz  + vz + bz);
      float rg  = sigmoid_f(xr  + vr + br);
      float hh  = tanh_f(xhv + rg*(vh + bh));
      float hnv = z*hprev + (1.0f - z)*hh;
      hprev = hnv;
      _Float16 hb = (_Float16)hnv;
      // sc1 write-through: lands at MALL, the consumers' coherence point
      __hip_atomic_store((unsigned short*)hn + (size_t)(((u >> 3) << 6) + sg)*8 + (u & 7),
                         __builtin_bit_cast(unsigned short, hb),
                         __ATOMIC_RELAXED, __HIP_MEMORY_SCOPE_AGENT);
      if ((sg >> 3) == mm)
        ret[(size_t)((((sg & 7)*32 + t) << 3) + mm)*256 + (u & 255)] = hnv;
      if (t == 31 && sg >= 56)
        st[(size_t)(sg - 56)*UNITS + u] = hnv;
    }
    if (t < TSTEPS - 1)
      half_barrier(bar, half, idxInHalf, t);
  }
}

extern "C" void kernel_launch(void* const* d_in, const int* in_sizes, int n_in,
                              void* d_out, int out_size, void* d_ws, size_t ws_size,
                              hipStream_t stream) {
  const float* x  = (const float*)d_in[0];
  const float* h0 = (const float*)d_in[1];
  const float* W  = (const float*)d_in[2];
  const float* U  = (const float*)d_in[3];
  const float* b  = (const float*)d_in[4];
  float* ret = (float*)d_out;
  float* st  = ret + 524288;

  char* p = (char*)d_ws;
  _Float16* Ut = (_Float16*)p; p += 25165824;
  _Float16* Wt = (_Float16*)p; p += 25165824;
  _Float16* xh = (_Float16*)p; p += 1048576;
  _Float16* xpf = (_Float16*)p; p += 25165824;              // 64x32x6144 f16
  _Float16* hRing = (_Float16*)p; p += 33ull * HSTRIDE * 2; // 8.25 MB
  unsigned* bar = (unsigned*)p; p += 2560;

  transpose_prep<<<dim3(96,32,2), 256, 0, stream>>>(W, U, Wt, Ut, x, h0, xh, hRing, bar);
  xp_gemm<<<dim3(192,2), 512, 0, stream>>>(xh, Wt, b, xpf);

  const float* brec = b + NC;
  void* args[] = { (void*)&Ut, (void*)&xpf, (void*)&brec, (void*)&h0,
                   (void*)&hRing, (void*)&ret, (void*)&st, (void*)&bar };
  hipLaunchCooperativeKernel((const void*)gru_persist, dim3(256), dim3(512),
                             args, 0, stream);
}

// Round 20
// 250.131 us; speedup vs baseline: 1.3517x; 1.0882x over previous
//
#include <hip/hip_runtime.h>
#include <hip/hip_bf16.h>

typedef _Float16 f16x8 __attribute__((ext_vector_type(8)));
typedef float f32x4 __attribute__((ext_vector_type(4)));
typedef unsigned long long ull;

#define UNITS   2048
#define NC      6144
#define TSTEPS  32
#define HSTRIDE 131072   // one h buffer: 64 seqs x 2048 units fp16 (blocked layout)

__device__ __forceinline__ float sigmoid_f(float v){ return 1.0f/(1.0f+__expf(-v)); }
__device__ __forceinline__ float tanh_f(float v){ return 2.0f/(1.0f+__expf(-2.0f*v)) - 1.0f; }

// ---- fused transpose+prep: W,U (2048x6144 f32) -> Wt,Ut (6144x2048 f16);
//      side-band: x cast, hRing[0] init, barrier zero ----
__global__ __launch_bounds__(256) void transpose_prep(
    const float* __restrict__ W, const float* __restrict__ U,
    _Float16* __restrict__ Wt, _Float16* __restrict__ Ut,
    const float* __restrict__ x, const float* __restrict__ h0,
    _Float16* __restrict__ xh, _Float16* __restrict__ hRing,
    unsigned* __restrict__ bar)
{
  __shared__ float tile[64][65];
  int tid = threadIdx.x;
  int lin = blockIdx.x + 96*(blockIdx.y + 32*blockIdx.z);

  // distributed prep work (each selected block does one 256-elem chunk)
  if (lin < 2048) {
    int i = lin*256 + tid;
    xh[i] = (_Float16)x[i];
  } else if (lin < 2560) {
    int i = (lin - 2048)*256 + tid;
    int s = i >> 11, u = i & 2047;
    float v = h0[((s & 7) << 11) + u];
    hRing[(((u >> 3) << 6) + s)*8 + (u & 7)] = (_Float16)v;
  } else if (lin == 2560) {
    for (int i = tid; i < 640; i += 256) bar[i] = 0;
  }

  const float* src = blockIdx.z ? U : W;
  _Float16* dst = blockIdx.z ? Ut : Wt;
  int n0 = blockIdx.x*64, k0 = blockIdx.y*64;

  // read: f32x4 per lane, 4 passes (16 k-rows x 64 n each)
  #pragma unroll
  for (int p = 0; p < 4; ++p) {
    int r = p*16 + (tid >> 4);
    int nq = tid & 15;
    f32x4 v = *(const f32x4*)(src + (size_t)(k0+r)*NC + n0 + nq*4);
    tile[r][nq*4+0] = v[0];
    tile[r][nq*4+1] = v[1];
    tile[r][nq*4+2] = v[2];
    tile[r][nq*4+3] = v[3];
  }
  __syncthreads();
  // write: f16x8 per lane, 2 passes (32 n-rows x 64 k each)
  #pragma unroll
  for (int p = 0; p < 2; ++p) {
    int row = p*32 + (tid >> 3);
    int k8 = (tid & 7)*8;
    f16x8 o;
    #pragma unroll
    for (int j = 0; j < 8; ++j) o[j] = (_Float16)tile[k8+j][row];
    *(f16x8*)(dst + (size_t)(n0+row)*UNITS + k0 + k8) = o;
  }
}

// ---- xp GEMM: grid (96 n, 2 bt-halves of 128 rows), 512 threads, f16 out ----
__global__ __launch_bounds__(512) void xp_gemm(
    const _Float16* __restrict__ xh, const _Float16* __restrict__ Wt,
    const float* __restrict__ bin, _Float16* __restrict__ xpf)
{
  __shared__ __align__(16) short sB[64*256];   // 32 KB, [col][k256] swizzled
  int n0 = blockIdx.x*64, bt0 = blockIdx.y*128;
  int tid = threadIdx.x;
  int lane = tid & 63, w = tid >> 6;
  int wm = w & 3, wn = w >> 2;
  int nl = lane & 15, kg = lane >> 4;
  f32x4 acc[2][2] = {{{0,0,0,0},{0,0,0,0}},{{0,0,0,0},{0,0,0,0}}};
  for (int l = 0; l < 8; ++l) {
    __syncthreads();
    #pragma unroll
    for (int i = 0; i < 4; ++i) {
      int e = tid + i*512;
      int col = e >> 5, ch = e & 31;
      f16x8 v = *(const f16x8*)(Wt + (size_t)(n0+col)*UNITS + l*256 + ch*8);
      int off = ((col<<9) | (ch<<4)) ^ ((col&7)<<4);
      *(f16x8*)((char*)sB + off) = v;
    }
    __syncthreads();
    #pragma unroll
    for (int kk = 0; kk < 256; kk += 32) {
      f16x8 a[2];
      #pragma unroll
      for (int sub = 0; sub < 2; ++sub) {
        int row = bt0 + wm*32 + sub*16 + nl;
        a[sub] = *(const f16x8*)(xh + ((size_t)row*8 + l)*256 + kg*8 + kk);
      }
      #pragma unroll
      for (int nt = 0; nt < 2; ++nt) {
        int col = wn*32 + nt*16 + nl;
        int off = ((col<<9) | ((kk + kg*8)<<1)) ^ ((col&7)<<4);
        f16x8 bfr = *(const f16x8*)((const char*)sB + off);
        #pragma unroll
        for (int sub = 0; sub < 2; ++sub)
          acc[sub][nt] = __builtin_amdgcn_mfma_f32_16x16x32_f16(a[sub], bfr, acc[sub][nt], 0,0,0);
      }
    }
    #pragma unroll
    for (int sub = 0; sub < 2; ++sub) {
      int orow = bt0 + wm*32 + sub*16 + kg*4;
      #pragma unroll
      for (int nt = 0; nt < 2; ++nt) {
        int col = n0 + wn*32 + nt*16 + nl;
        float bv = bin[col];
        #pragma unroll
        for (int r = 0; r < 4; ++r) {
          int rr = orow + r;
          int b_ = rr >> 5, t_ = rr & 31;
          xpf[(size_t)((l*8 + b_)*32 + t_)*NC + col] = (_Float16)(acc[sub][nt][r] + bv);
        }
      }
    }
  }
}

// ---- tree barrier, merged root/publication (champion, unchanged) ----
__device__ __forceinline__ void half_barrier(unsigned* bar, int half, int idxInHalf, int t)
{
  __syncthreads();   // compiler emits s_waitcnt vmcnt(0) here: h stores at MALL
  if (threadIdx.x == 0) {
    unsigned* grp  = bar + (half*8 + (idxInHalf & 7))*32;
    unsigned* root = bar + (16 + half)*32;
    unsigned tgt = (unsigned)(t + 1);
    unsigned a = __hip_atomic_fetch_add(grp, 1u, __ATOMIC_RELAXED, __HIP_MEMORY_SCOPE_AGENT) + 1u;
    if (a == tgt*16u)
      __hip_atomic_fetch_add(root, 1u, __ATOMIC_RELAXED, __HIP_MEMORY_SCOPE_AGENT);
    while (__hip_atomic_load(root, __ATOMIC_RELAXED, __HIP_MEMORY_SCOPE_AGENT) < tgt*8u)
      __builtin_amdgcn_s_sleep(1);
  }
  __syncthreads();
  __builtin_amdgcn_fence(__ATOMIC_ACQUIRE, "workgroup");
}

// ---- persistent GRU (champion, byte-identical to R14/R16) ----
__global__ __launch_bounds__(512, 2) void gru_persist(
    const _Float16* __restrict__ Ut, const _Float16* __restrict__ xpf,
    const float* __restrict__ brec, const float* __restrict__ h0,
    _Float16* __restrict__ hRing,
    float* __restrict__ ret, float* __restrict__ st, unsigned* __restrict__ bar)
{
  __shared__ __align__(16) float sRed[48*288];   // 55.3 KB padded partials

  int tid = threadIdx.x;
  int lane = tid & 63, kq = tid >> 6;       // 8 waves = 8 k-slices of 256
  int half = blockIdx.x & 1;
  int idxInHalf = blockIdx.x >> 1;
  int u0 = idxInHalf * 16;
  int s0 = half * 32;
  int nl = lane & 15, kg = lane >> 4;
  int redidx = lane*4 + (lane>>3)*4;

  // U fragments resident: 24 x f16x8 = 96 regs, pinned against remat
  f16x8 uw[3][8];
  #pragma unroll
  for (int g = 0; g < 3; ++g)
    #pragma unroll
    for (int kk = 0; kk < 8; ++kk) {
      uw[g][kk] = *(const f16x8*)(Ut + (size_t)(g*UNITS + u0 + nl)*UNITS + kq*256 + kk*32 + kg*8);
      asm volatile("" : "+v"(uw[g][kk]));
    }

  // flat epilogue ownership: thread -> (s_local = tid>>4, u_local = tid&15)
  int s_local = tid >> 4, u_local = tid & 15;
  int sg = s0 + s_local;
  int u  = u0 + u_local;
  int mE = s_local >> 4, kgE = (s_local >> 2) & 3, rE = s_local & 3;
  int laneE = kgE*16 + u_local;
  int ridxE = laneE*4 + (laneE>>3)*4 + rE;
  int mm = u0 >> 8;

  float bz = brec[u], br = brec[2048+u], bh = brec[4096+u];
  float hprev = h0[((sg & 7) << 11) + u];

  for (int t = 0; t < TSTEPS; ++t) {
    const _Float16* hc = hRing + (size_t)t*HSTRIDE;
    _Float16*       hn = hRing + (size_t)(t+1)*HSTRIDE;

    // xp(t) loads issue before the MFMA chain; latency hides under it
    const _Float16* xrow = xpf + ((size_t)sg*32 + t)*NC;
    float xz  = (float)xrow[u];
    float xr  = (float)xrow[2048+u];
    float xhv = (float)xrow[4096+u];

    f32x4 a0z={0,0,0,0}, a0r={0,0,0,0}, a0h={0,0,0,0};
    f32x4 a1z={0,0,0,0}, a1r={0,0,0,0}, a1h={0,0,0,0};
    // blocked layout: elem (s,k) at ((k>>3)*64 + s)*8 + (k&7); coalesced b128
    const _Float16* Ab = hc + (size_t)(((kq*32 + kg)*64) + s0 + nl)*8;
    #pragma unroll
    for (int kk = 0; kk < 8; ++kk) {
      f16x8 av0 = *(const f16x8*)(Ab + kk*2048);
      f16x8 av1 = *(const f16x8*)(Ab + kk*2048 + 128);
      a0z = __builtin_amdgcn_mfma_f32_16x16x32_f16(av0, uw[0][kk], a0z, 0,0,0);
      a1z = __builtin_amdgcn_mfma_f32_16x16x32_f16(av1, uw[0][kk], a1z, 0,0,0);
      a0r = __builtin_amdgcn_mfma_f32_16x16x32_f16(av0, uw[1][kk], a0r, 0,0,0);
      a1r = __builtin_amdgcn_mfma_f32_16x16x32_f16(av1, uw[1][kk], a1r, 0,0,0);
      a0h = __builtin_amdgcn_mfma_f32_16x16x32_f16(av0, uw[2][kk], a0h, 0,0,0);
      a1h = __builtin_amdgcn_mfma_f32_16x16x32_f16(av1, uw[2][kk], a1h, 0,0,0);
    }

    // publish partials (16 slots: kq*2 + seq-half-of-32)
    {
      float* rp0 = &sRed[((kq*2 + 0)*3)*288 + redidx];
      *(f32x4*)(rp0)        = a0z;
      *(f32x4*)(rp0 + 288)  = a0r;
      *(f32x4*)(rp0 + 576)  = a0h;
      float* rp1 = &sRed[((kq*2 + 1)*3)*288 + redidx];
      *(f32x4*)(rp1)        = a1z;
      *(f32x4*)(rp1 + 288)  = a1r;
      *(f32x4*)(rp1 + 576)  = a1h;
    }
    __syncthreads();

    // flat epilogue: 512 threads, each reduces 8 partials for its (s,u)
    {
      float vz = 0.f, vr = 0.f, vh = 0.f;
      #pragma unroll
      for (int q = 0; q < 8; ++q) {
        const float* base = &sRed[((q*2 + mE)*3)*288 + ridxE];
        vz += base[0];
        vr += base[288];
        vh += base[576];
      }
      float z   = sigmoid_f(xz  + vz + bz);
      float rg  = sigmoid_f(xr  + vr + br);
      float hh  = tanh_f(xhv + rg*(vh + bh));
      float hnv = z*hprev + (1.0f - z)*hh;
      hprev = hnv;
      _Float16 hb = (_Float16)hnv;
      // sc1 write-through: lands at MALL, the consumers' coherence point
      __hip_atomic_store((unsigned short*)hn + (size_t)(((u >> 3) << 6) + sg)*8 + (u & 7),
                         __builtin_bit_cast(unsigned short, hb),
                         __ATOMIC_RELAXED, __HIP_MEMORY_SCOPE_AGENT);
      if ((sg >> 3) == mm)
        ret[(size_t)((((sg & 7)*32 + t) << 3) + mm)*256 + (u & 255)] = hnv;
      if (t == 31 && sg >= 56)
        st[(size_t)(sg - 56)*UNITS + u] = hnv;
    }
    if (t < TSTEPS - 1)
      half_barrier(bar, half, idxInHalf, t);
  }
}

extern "C" void kernel_launch(void* const* d_in, const int* in_sizes, int n_in,
                              void* d_out, int out_size, void* d_ws, size_t ws_size,
                              hipStream_t stream) {
  const float* x  = (const float*)d_in[0];
  const float* h0 = (const float*)d_in[1];
  const float* W  = (const float*)d_in[2];
  const float* U  = (const float*)d_in[3];
  const float* b  = (const float*)d_in[4];
  float* ret = (float*)d_out;
  float* st  = ret + 524288;

  char* p = (char*)d_ws;
  _Float16* Ut = (_Float16*)p; p += 25165824;
  _Float16* Wt = (_Float16*)p; p += 25165824;
  _Float16* xh = (_Float16*)p; p += 1048576;
  _Float16* xpf = (_Float16*)p; p += 25165824;              // 64x32x6144 f16
  _Float16* hRing = (_Float16*)p; p += 33ull * HSTRIDE * 2; // 8.25 MB
  unsigned* bar = (unsigned*)p; p += 2560;

  transpose_prep<<<dim3(96,32,2), 256, 0, stream>>>(W, U, Wt, Ut, x, h0, xh, hRing, bar);
  xp_gemm<<<dim3(96,2), 512, 0, stream>>>(xh, Wt, b, xpf);

  const float* brec = b + NC;
  void* args[] = { (void*)&Ut, (void*)&xpf, (void*)&brec, (void*)&h0,
                   (void*)&hRing, (void*)&ret, (void*)&st, (void*)&bar };
  hipLaunchCooperativeKernel((const void*)gru_persist, dim3(256), dim3(512),
                             args, 0, stream);
}